// Round 13
// baseline (160.202 us; speedup 1.0000x reference)
//
#include <hip/hip_runtime.h>
#include <hip/hip_bf16.h>
#include <hip/hip_fp8.h>

// Problem shape (fixed by setup_inputs)
#define SEQ   16384
#define DIN_  2048
#define DOUT_ 1024
#define NE_   8
#define TPE   (SEQ / NE_)   // 2048 tokens per expert
#define NG    (DIN_ / 128)  // 16 scale groups of K=128

typedef float f32x4 __attribute__((ext_vector_type(4)));
typedef int   i32x4 __attribute__((ext_vector_type(4)));
typedef int   i32x8 __attribute__((ext_vector_type(8)));

// async global->LDS, 16B per lane; LDS dest must be wave-uniform base + lane*16.
#define GLD(gp, lp) __builtin_amdgcn_global_load_lds( \
    (const __attribute__((address_space(1))) unsigned int*)(gp), \
    (__attribute__((address_space(3))) unsigned int*)(lp), 16, 0, 0)

// Reference fp8 rounding (divide hoisted): clip(v*sinv,+-448) -> e4m3fn RNE byte
__device__ __forceinline__ unsigned char fp8_byte_m(float v, float sinv) {
    float r = v * sinv;
    r = fminf(fmaxf(r, -448.0f), 448.0f);
    __hip_fp8_e4m3 q(r);
    return (unsigned char)q.__x;
}

// ---------------- activation quant: 1x128 tiles -> fp8 + sxT, 4 rows/block -------------
// sxT layout: [16 groups][SEQ] f32
__global__ __launch_bounds__(256) void quant_x_kernel(const float* __restrict__ X,
                                                      unsigned char* __restrict__ Xq,
                                                      float* __restrict__ sxT) {
    const int t    = threadIdx.x;
    const int lane = t & 63;
    const int wave = t >> 6;
    const int tile = wave * 4 + (lane >> 4);   // 0..15 (group)
    const int sub  = lane & 15;
    const size_t off = (size_t)tile * 128 + sub * 8;

    const int row0 = blockIdx.x * 4;
    float4 v0[4], v1[4];
    float mx[4];
    #pragma unroll
    for (int r = 0; r < 4; ++r) {
        const float* p = X + (size_t)(row0 + r) * DIN_ + off;
        v0[r] = *(const float4*)p;
        v1[r] = *(const float4*)(p + 4);
        mx[r] = fmaxf(fmaxf(fmaxf(fabsf(v0[r].x), fabsf(v0[r].y)),
                            fmaxf(fabsf(v0[r].z), fabsf(v0[r].w))),
                      fmaxf(fmaxf(fabsf(v1[r].x), fabsf(v1[r].y)),
                            fmaxf(fabsf(v1[r].z), fabsf(v1[r].w))));
    }
    #pragma unroll
    for (int o = 1; o < 16; o <<= 1) {
        #pragma unroll
        for (int r = 0; r < 4; ++r)
            mx[r] = fmaxf(mx[r], __shfl_xor(mx[r], o, 64));
    }
    #pragma unroll
    for (int r = 0; r < 4; ++r) {
        const float s    = fmaxf(mx[r], 1e-12f) / 448.0f;
        const float sinv = 1.0f / s;
        if (sub == 0) sxT[(size_t)tile * SEQ + row0 + r] = s;
        unsigned lo = (unsigned)fp8_byte_m(v0[r].x, sinv)
                    | ((unsigned)fp8_byte_m(v0[r].y, sinv) << 8)
                    | ((unsigned)fp8_byte_m(v0[r].z, sinv) << 16)
                    | ((unsigned)fp8_byte_m(v0[r].w, sinv) << 24);
        unsigned hi = (unsigned)fp8_byte_m(v1[r].x, sinv)
                    | ((unsigned)fp8_byte_m(v1[r].y, sinv) << 8)
                    | ((unsigned)fp8_byte_m(v1[r].z, sinv) << 16)
                    | ((unsigned)fp8_byte_m(v1[r].w, sinv) << 24);
        uint2 u; u.x = lo; u.y = hi;
        *(uint2*)(Xq + (size_t)(row0 + r) * DIN_ + off) = u;
    }
}

// ---------------- weight quant: 128x128 blocks -> fp8 + sw -----------------------------
// sw layout: [64 o-blocks][16 k-groups] f32
__global__ __launch_bounds__(256) void quant_w_kernel(const float* __restrict__ W,
                                                      unsigned char* __restrict__ Wq,
                                                      float* __restrict__ sw) {
    const int rb = blockIdx.x >> 4;
    const int cb = blockIdx.x & 15;
    const int t  = threadIdx.x;

    const float* base = W + (size_t)(rb * 128) * DIN_ + cb * 128;
    const int r0 = t >> 5;
    const int c0 = (t & 31) * 4;

    float4 v[16];
    float m = 0.0f;
    #pragma unroll
    for (int i = 0; i < 16; ++i) {
        v[i] = *(const float4*)(base + (size_t)(i * 8 + r0) * DIN_ + c0);
        m = fmaxf(m, fmaxf(fmaxf(fabsf(v[i].x), fabsf(v[i].y)),
                           fmaxf(fabsf(v[i].z), fabsf(v[i].w))));
    }
    #pragma unroll
    for (int off = 1; off < 64; off <<= 1)
        m = fmaxf(m, __shfl_xor(m, off, 64));
    __shared__ float smx[4];
    if ((t & 63) == 0) smx[t >> 6] = m;
    __syncthreads();
    const float amax = fmaxf(fmaxf(smx[0], smx[1]), fmaxf(smx[2], smx[3]));
    const float s    = fmaxf(amax, 1e-12f) / 448.0f;
    const float sinv = 1.0f / s;
    if (t == 0) sw[rb * 16 + cb] = s;

    unsigned char* obase = Wq + (size_t)(rb * 128) * DIN_ + cb * 128;
    #pragma unroll
    for (int i = 0; i < 16; ++i) {
        unsigned u = (unsigned)fp8_byte_m(v[i].x, sinv)
                   | ((unsigned)fp8_byte_m(v[i].y, sinv) << 8)
                   | ((unsigned)fp8_byte_m(v[i].z, sinv) << 16)
                   | ((unsigned)fp8_byte_m(v[i].w, sinv) << 24);
        *(unsigned int*)(obase + (size_t)(i * 8 + r0) * DIN_ + c0) = u;
    }
}

// ---------------- grouped GEMM: fp8, 256x256 tile, K-group 128, mfma_scale -------------
// out = sum_g sx[row,g]*sw[ob,g] * (sum_{k in g} qx*qw)   (inner sum = one MFMA K=128)
// 8 waves (2M x 4N), per-wave 128x64 = acc[8][4] f32x4.
// LDS: A(buf)[256][128B] @ buf*32768 ; B(buf) @ 65536+buf*32768 ; sx tile [16][256]f32
// @131072 ; sw [2][16]f32 @147456. Swizzle byte p ^= ((p>>7)&7)<<4 (both-sides, bank-
// optimal for the two-b128 32B fragment reads). R3 proved layout+intrinsic correctness.
// Fix vs R3: MFMA results consumed via 2-deep pn pipeline (cluster m's scale-FMA issued
// after cluster m+2's MFMAs) -> no MFMA->VALU latency serialization.
// Ledger/group: top 21 lgkm (b 8, aA 8, sxv03 4, sw 1); ph1 lgkm(0); ph2 reads aB 8 +
// sxv47 4, lgkm(0); boundary: barrier, stage(g+2) [8 GLD], vmcnt(8|0), barrier, top(g+1).
__global__ __launch_bounds__(512, 2) void gemm_kernel(const unsigned char* __restrict__ Xq,
                                                      const unsigned char* __restrict__ Wq,
                                                      const float* __restrict__ sxT,
                                                      const float* __restrict__ swg_,
                                                      float* __restrict__ out) {
    __shared__ __align__(16) unsigned char lds[147584];

    // T1: bijective XCD swizzle; 256 blocks = 8 XCDs x 32 (one expert per XCD)
    const int bid  = blockIdx.x;
    const int wgid = (bid & 7) * 32 + (bid >> 3);
    const int e    = wgid >> 5;
    const int tile = wgid & 31;
    const int brow = tile >> 2;   // 0..7
    const int bcol = tile & 3;    // 0..3

    const int t    = threadIdx.x;
    const int lane = t & 63;
    const int wave = t >> 6;
    const int wm   = wave >> 2;   // 0..1
    const int wn   = wave & 3;    // 0..3
    const int fl   = lane & 15;
    const unsigned kc  = (unsigned)(lane >> 4);   // 32B k-chunk
    const unsigned sxr = (unsigned)((lane >> 4) * 4);

    const int row0 = e * TPE + brow * 256;
    const unsigned char* Xt = Xq + (size_t)row0 * DIN_;
    const unsigned char* Wt = Wq + (size_t)(e * DOUT_ + bcol * 256) * DIN_;

    // stage group j: A 32KB (4 GLD) + B 32KB (4 GLD); linear dest, inv-swizzled source
    auto stage = [&](int j) {
        if (j >= NG) return;
        const unsigned ab = (unsigned)(j & 1) * 32768u;
        #pragma unroll
        for (int i = 0; i < 4; ++i) {
            const unsigned p = (unsigned)i * 8192u + (unsigned)t * 16u;
            const unsigned q = p ^ (((p >> 7) & 7u) << 4);
            GLD(Xt + (size_t)(q >> 7) * DIN_ + j * 128 + (q & 127u), &lds[ab + p]);
        }
        #pragma unroll
        for (int i = 0; i < 4; ++i) {
            const unsigned p = (unsigned)i * 8192u + (unsigned)t * 16u;
            const unsigned q = p ^ (((p >> 7) & 7u) << 4);
            GLD(Wt + (size_t)(q >> 7) * DIN_ + j * 128 + (q & 127u),
                &lds[65536u + ab + p]);
        }
    };

    // fp8 fragment: 32B at (row, kc) = two swizzled b128
    auto ldf8 = [&](unsigned base, unsigned row) -> i32x8 {
        const unsigned p0 = row * 128u + kc * 32u;
        const unsigned s  = ((p0 >> 7) & 7u) << 4;
        i32x4 lo = *(const i32x4*)&lds[base + (p0 ^ s)];
        i32x4 hi = *(const i32x4*)&lds[base + ((p0 + 16u) ^ s)];
        return __builtin_shufflevector(lo, hi, 0, 1, 2, 3, 4, 5, 6, 7);
    };

    i32x8 bfr[4], aA[4], aB[4];
    f32x4 sxv03[4], sxv47[4];
    float swg;
    f32x4 acc[8][4] = {};
    const f32x4 zero = {0.f, 0.f, 0.f, 0.f};

    #define AB_(buf) ((unsigned)(buf) * 32768u)
    #define BB_(buf) (65536u + (unsigned)(buf) * 32768u)
    #define MFS(a, b) __builtin_amdgcn_mfma_scale_f32_16x16x128_f8f6f4( \
        a, b, zero, 0, 0, 0, 0x7f7f7f7f, 0, 0x7f7f7f7f)
    #define TOP_READS(buf, g) \
      { _Pragma("unroll") for (int n_ = 0; n_ < 4; ++n_) \
            bfr[n_] = ldf8(BB_(buf), (unsigned)(wn * 64 + n_ * 16 + fl)); \
        _Pragma("unroll") for (int m_ = 0; m_ < 4; ++m_) \
            aA[m_] = ldf8(AB_(buf), (unsigned)(wm * 128 + m_ * 16 + fl)); \
        _Pragma("unroll") for (int m_ = 0; m_ < 4; ++m_) \
            sxv03[m_] = *(const f32x4*)&lds[131072u + (unsigned)(g) * 1024u \
                + (unsigned)(wm * 128 + m_ * 16) * 4u + sxr * 4u]; \
        swg = *(const float*)&lds[147456u + (unsigned)(((wn >> 1) << 4) + (g)) * 4u]; }
    // 2-deep pn pipeline: cluster m's scale-FMA after cluster m+2's MFMA issue
    #define PHASE_MFMA(mo, afr, sxv) \
      { f32x4 pnA[4], pnB[4]; \
        const f32x4 sf0 = sxv[0] * swg, sf1 = sxv[1] * swg; \
        const f32x4 sf2 = sxv[2] * swg, sf3 = sxv[3] * swg; \
        _Pragma("unroll") for (int n_ = 0; n_ < 4; ++n_) pnA[n_] = MFS(afr[0], bfr[n_]); \
        _Pragma("unroll") for (int n_ = 0; n_ < 4; ++n_) pnB[n_] = MFS(afr[1], bfr[n_]); \
        _Pragma("unroll") for (int n_ = 0; n_ < 4; ++n_) acc[(mo)+0][n_] += pnA[n_] * sf0; \
        _Pragma("unroll") for (int n_ = 0; n_ < 4; ++n_) pnA[n_] = MFS(afr[2], bfr[n_]); \
        _Pragma("unroll") for (int n_ = 0; n_ < 4; ++n_) acc[(mo)+1][n_] += pnB[n_] * sf1; \
        _Pragma("unroll") for (int n_ = 0; n_ < 4; ++n_) pnB[n_] = MFS(afr[3], bfr[n_]); \
        _Pragma("unroll") for (int n_ = 0; n_ < 4; ++n_) acc[(mo)+2][n_] += pnA[n_] * sf2; \
        _Pragma("unroll") for (int n_ = 0; n_ < 4; ++n_) acc[(mo)+3][n_] += pnB[n_] * sf3; }

    // ---- prologue ----
    // issue order matters for the vmcnt(8): sx(2), sw(1), stage0(8) | stage1(8 newest)
    #pragma unroll
    for (int i = 0; i < 2; ++i) {
        const unsigned p = (unsigned)i * 8192u + (unsigned)t * 16u;
        GLD((const unsigned char*)sxT + ((size_t)(p >> 10) * SEQ + row0) * 4 + (p & 1023u),
            &lds[131072u + p]);
    }
    float swv = 0.0f;
    if (t < 32) swv = swg_[(size_t)(e * 8 + bcol * 2 + (t >> 4)) * 16 + (t & 15)];
    stage(0); stage(1);
    asm volatile("s_waitcnt vmcnt(8)" ::: "memory");   // sx, sw, stage0 landed
    if (t < 32) *(float*)&lds[147456u + (unsigned)t * 4u] = swv;
    asm volatile("s_waitcnt lgkmcnt(0)" ::: "memory");
    __builtin_amdgcn_s_barrier();
    TOP_READS(0, 0)

    for (int g = 0; g < NG; ++g) {
        const int buf = g & 1;

        // ---- phase 1: m0-3 ----
        asm volatile("s_waitcnt lgkmcnt(0)" ::: "memory");   // top reads drained
        __builtin_amdgcn_sched_barrier(0);
        __builtin_amdgcn_s_setprio(1);
        PHASE_MFMA(0, aA, sxv03)
        __builtin_amdgcn_s_setprio(0);

        // ---- phase 2: m4-7 (own-phase reads; aA/sxv03 regs retire) ----
        #pragma unroll
        for (int m_ = 0; m_ < 4; ++m_)
            aB[m_] = ldf8(AB_(buf), (unsigned)(wm * 128 + (m_ + 4) * 16 + fl));
        #pragma unroll
        for (int m_ = 0; m_ < 4; ++m_)
            sxv47[m_] = *(const f32x4*)&lds[131072u + (unsigned)g * 1024u
                + (unsigned)(wm * 128 + (m_ + 4) * 16) * 4u + sxr * 4u];
        asm volatile("s_waitcnt lgkmcnt(0)" ::: "memory");
        __builtin_amdgcn_sched_barrier(0);
        __builtin_amdgcn_s_setprio(1);
        PHASE_MFMA(4, aB, sxv47)
        __builtin_amdgcn_s_setprio(0);

        // ---- boundary ----
        if (g < NG - 1) {
            __builtin_amdgcn_s_barrier();         // all waves drained buf(g) reads
            stage(g + 2);
            if (g < NG - 2) asm volatile("s_waitcnt vmcnt(8)" ::: "memory");
            else            asm volatile("s_waitcnt vmcnt(0)" ::: "memory");
            __builtin_amdgcn_s_barrier();         // group g+1 resident
            TOP_READS(buf ^ 1, g + 1)
        }
    }

    // epilogue: C/D mapping col = lane&15, row = (lane>>4)*4 + j (shape-determined)
    const int orow0 = e * TPE + brow * 256 + wm * 128;
    const int ocol0 = bcol * 256 + wn * 64;
    const int rl = (lane >> 4) * 4;
    const int cl = lane & 15;
    #pragma unroll
    for (int m = 0; m < 8; ++m)
        #pragma unroll
        for (int n = 0; n < 4; ++n)
            #pragma unroll
            for (int j = 0; j < 4; ++j) {
                const int r = orow0 + m * 16 + rl + j;
                const int c = ocol0 + n * 16 + cl;
                out[(size_t)r * DOUT_ + c] = acc[m][n][j];
            }
}

extern "C" void kernel_launch(void* const* d_in, const int* in_sizes, int n_in,
                              void* d_out, int out_size, void* d_ws, size_t ws_size,
                              hipStream_t stream) {
    const float* x = (const float*)d_in[0];
    // d_in[1] = tokens_per_expert: reference assumes equal split, unused.
    const float* w = (const float*)d_in[2];
    float* out = (float*)d_out;

    // workspace: xq 32MiB | wq 16MiB | sxT 1MiB | sw 4KiB
    unsigned char* xq = (unsigned char*)d_ws;
    unsigned char* wq = xq + (size_t)SEQ * DIN_;
    float* sxT = (float*)(wq + (size_t)NE_ * DOUT_ * DIN_);
    float* sw  = sxT + (size_t)NG * SEQ;

    quant_x_kernel<<<SEQ / 4, 256, 0, stream>>>(x, xq, sxT);
    quant_w_kernel<<<(NE_ * DOUT_ / 128) * (DIN_ / 128), 256, 0, stream>>>(w, wq, sw);
    gemm_kernel<<<NE_ * (TPE / 256) * (DOUT_ / 256), 512, 0, stream>>>(xq, wq, sxT, sw, out);
}